// Round 8
// baseline (741.235 us; speedup 1.0000x reference)
//
#include <hip/hip_runtime.h>
#include <hip/hip_bf16.h>
#include <hip/hip_fp16.h>

#define N_NODES 128000
#define E_EDGES 2048000
#define G_GRAPHS 512
#define D_IN 12
#define D_H 64
#define N_CLS 10
#define BN_EPS 1e-5f
#define NB 1000        // buckets = dst >> 7 (128-node ranges)
#define TILE 8192      // edges per k_bin block (250 blocks)

// ---------------- CSR build ----------------

__global__ __launch_bounds__(256) void k_hist(const int* __restrict__ dst, int* __restrict__ deg) {
    int e = blockIdx.x * 256 + threadIdx.x;
    if (e < E_EDGES) atomicAdd(&deg[dst[e]], 1);
}

__global__ __launch_bounds__(256) void k_scan1(const int* __restrict__ deg, int* __restrict__ bsum) {
    __shared__ int sm[256];
    int t = threadIdx.x;
    int base = blockIdx.x * 1024 + t * 4;
    int s = deg[base] + deg[base + 1] + deg[base + 2] + deg[base + 3];
    sm[t] = s;
    __syncthreads();
    for (int off = 128; off > 0; off >>= 1) {
        if (t < off) sm[t] += sm[t + off];
        __syncthreads();
    }
    if (t == 0) bsum[blockIdx.x] = sm[0];
}

__global__ __launch_bounds__(256) void k_scan_top(int* __restrict__ bsum, int nb) {
    __shared__ int sm[256];
    int t = threadIdx.x;
    int v = (t < nb) ? bsum[t] : 0;
    sm[t] = v;
    __syncthreads();
    for (int off = 1; off < 256; off <<= 1) {
        int x = 0;
        if (t >= off) x = sm[t - off];
        __syncthreads();
        sm[t] += x;
        __syncthreads();
    }
    if (t < nb) bsum[t] = sm[t] - v;  // exclusive
}

__global__ __launch_bounds__(256) void k_scan_down(const int* __restrict__ deg, const int* __restrict__ bsum,
                                                   int* __restrict__ offsets, int* __restrict__ cursor) {
    __shared__ int sm[256];
    int t = threadIdx.x;
    int blk = blockIdx.x;
    int base = blk * 1024 + t * 4;
    int d0 = deg[base], d1 = deg[base + 1], d2 = deg[base + 2], d3 = deg[base + 3];
    int s = d0 + d1 + d2 + d3;
    sm[t] = s;
    __syncthreads();
    for (int off = 1; off < 256; off <<= 1) {
        int x = 0;
        if (t >= off) x = sm[t - off];
        __syncthreads();
        sm[t] += x;
        __syncthreads();
    }
    int tbase = bsum[blk] + sm[t] - s;
    int p0 = tbase, p1 = tbase + d0, p2 = p1 + d1, p3 = p2 + d2;
    offsets[base] = p0;     cursor[base] = p0;
    offsets[base + 1] = p1; cursor[base + 1] = p1;
    offsets[base + 2] = p2; cursor[base + 2] = p2;
    offsets[base + 3] = p3; cursor[base + 3] = p3;
    if (blk == 0 && t == 0) offsets[N_NODES] = E_EDGES;
}

__global__ __launch_bounds__(256) void k_init_bcur(const int* __restrict__ offsets, int* __restrict__ bcur) {
    int b = blockIdx.x * 256 + threadIdx.x;
    if (b < NB) bcur[b] = offsets[b * 128];
}

// Phase 1: LDS-ranked binning into per-bucket contiguous runs (coalesced-ish writes)
__global__ __launch_bounds__(256) void k_bin(const int* __restrict__ src, const int* __restrict__ dst,
                                             const float2* __restrict__ attr, int* __restrict__ bcur,
                                             int4* __restrict__ stage) {
    __shared__ int hist[NB];
    __shared__ int base_s[NB];
    __shared__ int rk[TILE];  // packed bucket(10) << 13 | rank(13)
    const int t = threadIdx.x;
    const int e0 = blockIdx.x * TILE;
    for (int i = t; i < NB; i += 256) hist[i] = 0;
    __syncthreads();
    for (int i = t; i < TILE; i += 256) {
        int d = dst[e0 + i];
        int b = d >> 7;
        int r = atomicAdd(&hist[b], 1);
        rk[i] = (b << 13) | r;
    }
    __syncthreads();
    for (int i = t; i < NB; i += 256) {
        int cb = hist[i];
        base_s[i] = (cb > 0) ? atomicAdd(&bcur[i], cb) : 0;
    }
    __syncthreads();
    for (int i = t; i < TILE; i += 256) {
        int pr = rk[i];
        int b = pr >> 13, r = pr & 8191;
        float2 a = attr[e0 + i];
        stage[base_s[b] + r] = make_int4(src[e0 + i], __float_as_int(a.x), __float_as_int(a.y), dst[e0 + i]);
    }
}

// Phase 2: one block per bucket; exact CSR placement within an L2-resident window
__global__ __launch_bounds__(256) void k_final(const int* __restrict__ offsets, const int4* __restrict__ stage,
                                               int* __restrict__ cursor, int4* __restrict__ edges) {
    const int b = blockIdx.x;
    const int s0 = offsets[b * 128];
    const int s1 = offsets[(b + 1) * 128];
    for (int i = s0 + threadIdx.x; i < s1; i += 256) {
        int4 r = stage[i];
        int p = atomicAdd(&cursor[r.w], 1);
        edges[p] = r;
    }
}

// pack x [N,12] fp32 -> [N,16] fp16 (channels 12..15 = 0): 32B rows, always 1 line
__global__ __launch_bounds__(256) void k_pack_x(const float* __restrict__ x, __half* __restrict__ x16) {
    int idx = blockIdx.x * 256 + threadIdx.x;
    int n = idx >> 4, ch = idx & 15;
    x16[idx] = __float2half((ch < D_IN) ? x[n * D_IN + ch] : 0.f);
}

// ---------------- Layer 1 (12-dim input, 64-dim output, fp16 out) ----------------
// Neighbor gathers read fp16-packed x16 (1 line/edge); center+residual use exact fp32 x.
__global__ __launch_bounds__(256) void k_gine12(
    const float* __restrict__ x, const __half* __restrict__ x16, __half* __restrict__ hout,
    const int* __restrict__ off, const int4* __restrict__ edges,
    const float* __restrict__ We1, const float* __restrict__ be1,
    const float* __restrict__ W1, const float* __restrict__ b1,
    const float* __restrict__ g1, const float* __restrict__ bt1,
    const float* __restrict__ rm1, const float* __restrict__ rv1,
    const float* __restrict__ Wr, const float* __restrict__ br) {
    __shared__ float W1lds[D_IN * 64];
    __shared__ float Wrlds[D_IN * 64];
    __shared__ float u_lds[4][D_IN];
    __shared__ float x_lds[4][D_IN];
    const int t = threadIdx.x, w = t >> 6, c = t & 63;
    for (int i = t; i < D_IN * 64; i += 256) {
        W1lds[i] = W1[i];
        Wrlds[i] = Wr[i];
    }
    float we0 = 0.f, we1 = 0.f, bec = 0.f;
    if (c < D_IN) { we0 = We1[c]; we1 = We1[D_IN + c]; bec = be1[c]; }
    const float sj = g1[c] * rsqrtf(rv1[c] + BN_EPS);
    const float cj = (b1[c] - rm1[c]) * sj + bt1[c];
    const float brj = br[c];
    __syncthreads();

    const int n = blockIdx.x * 4 + w;
    const int rs = off[n], re = off[n + 1];
    const float xc = (c < D_IN) ? x[(size_t)n * D_IN + c] : 0.f;  // hoisted center load
    float acc = 0.f;
    for (int base = rs; base < re; base += 64) {
        const int cnt = min(64, re - base);
        int4 rec = make_int4(0, 0, 0, 0);
        if (c < cnt) rec = edges[base + c];
        for (int j = 0; j < cnt; j += 16) {
            __half hv[16];
#pragma unroll
            for (int u = 0; u < 16; ++u) {
                int idx = j + u; if (idx > cnt - 1) idx = cnt - 1;  // clamp: dup loads hit L1
                int s = __builtin_amdgcn_readlane(rec.x, idx);
                hv[u] = (c < D_IN) ? x16[(size_t)s * 16 + c] : __half(0.f);
            }
#pragma unroll
            for (int u = 0; u < 16; ++u) {
                if (j + u < cnt) {
                    float ax = __int_as_float(__builtin_amdgcn_readlane(rec.y, j + u));
                    float ay = __int_as_float(__builtin_amdgcn_readlane(rec.z, j + u));
                    acc += fmaxf(__half2float(hv[u]) + fmaf(ax, we0, fmaf(ay, we1, bec)), 0.f);
                }
            }
        }
    }
    if (c < D_IN) {
        x_lds[w][c] = xc;
        u_lds[w][c] = xc + acc;
    }
    float z = 0.f, r = 0.f;
#pragma unroll
    for (int k = 0; k < D_IN; ++k) {
        z = fmaf(u_lds[w][k], W1lds[k * 64 + c], z);
        r = fmaf(x_lds[w][k], Wrlds[k * 64 + c], r);
    }
    hout[(size_t)n * 64 + c] = __float2half(fmaxf(fmaf(z, sj, cj), 0.f) + r + brj);
}

// ---------------- Layers 2/3 (64-dim, fp16 h storage) ----------------
__global__ __launch_bounds__(256) void k_gine64(
    const __half* __restrict__ hin, __half* __restrict__ hout,
    const int* __restrict__ off, const int4* __restrict__ edges,
    const float* __restrict__ We, const float* __restrict__ be,
    const float* __restrict__ W, const float* __restrict__ b,
    const float* __restrict__ g, const float* __restrict__ bt,
    const float* __restrict__ rm, const float* __restrict__ rv) {
    __shared__ float Wlds[64 * 64];
    __shared__ float u_lds[4][64];
    const int t = threadIdx.x, w = t >> 6, c = t & 63;
    {
        const float4* W4 = (const float4*)W;
        float4* Wl4 = (float4*)Wlds;
#pragma unroll
        for (int i = t; i < 1024; i += 256) Wl4[i] = W4[i];
    }
    const float we0 = We[c], we1 = We[64 + c], bec = be[c];
    const float sj = g[c] * rsqrtf(rv[c] + BN_EPS);
    const float cj = (b[c] - rm[c]) * sj + bt[c];
    __syncthreads();

    const int n = blockIdx.x * 4 + w;
    const int rs = off[n], re = off[n + 1];
    const __half hc16 = hin[(size_t)n * 64 + c];  // hoisted center load
    float acc = 0.f;
    for (int base = rs; base < re; base += 64) {
        const int cnt = min(64, re - base);
        int4 rec = make_int4(0, 0, 0, 0);
        if (c < cnt) rec = edges[base + c];
        for (int j = 0; j < cnt; j += 16) {
            __half hv[16];
#pragma unroll
            for (int u = 0; u < 16; ++u) {
                int idx = j + u; if (idx > cnt - 1) idx = cnt - 1;  // clamp: dup loads hit L1
                int s = __builtin_amdgcn_readlane(rec.x, idx);
                hv[u] = hin[(size_t)s * 64 + c];  // 16 gathers in flight
            }
#pragma unroll
            for (int u = 0; u < 16; ++u) {
                if (j + u < cnt) {
                    float ax = __int_as_float(__builtin_amdgcn_readlane(rec.y, j + u));
                    float ay = __int_as_float(__builtin_amdgcn_readlane(rec.z, j + u));
                    acc += fmaxf(__half2float(hv[u]) + fmaf(ax, we0, fmaf(ay, we1, bec)), 0.f);
                }
            }
        }
    }
    const float hc = __half2float(hc16);
    u_lds[w][c] = hc + acc;
    float z = 0.f;
    const float4* u4 = (const float4*)u_lds[w];
#pragma unroll
    for (int k4 = 0; k4 < 16; ++k4) {
        float4 uu = u4[k4];
        z = fmaf(uu.x, Wlds[(k4 * 4 + 0) * 64 + c], z);
        z = fmaf(uu.y, Wlds[(k4 * 4 + 1) * 64 + c], z);
        z = fmaf(uu.z, Wlds[(k4 * 4 + 2) * 64 + c], z);
        z = fmaf(uu.w, Wlds[(k4 * 4 + 3) * 64 + c], z);
    }
    hout[(size_t)n * 64 + c] = __float2half(fmaxf(fmaf(z, sj, cj), 0.f) + hc);
}

// ---------------- Pool (mean+max per graph) + classifier ----------------
__global__ __launch_bounds__(256) void k_pool(
    const __half* __restrict__ h, const int* __restrict__ batch,
    const float* __restrict__ Wc1, const float* __restrict__ bc1,
    const float* __restrict__ Wc2, const float* __restrict__ bc2,
    float* __restrict__ out) {
    __shared__ float psum[4][64];
    __shared__ float pmax[4][64];
    __shared__ float pool[128];
    __shared__ float hid[64];
    const int t = threadIdx.x, w = t >> 6, c = t & 63;
    const int g = blockIdx.x;
    int lo = 0, hi = N_NODES;
    while (lo < hi) { int mid = (lo + hi) >> 1; if (batch[mid] < g) lo = mid + 1; else hi = mid; }
    int start = lo;
    hi = N_NODES;
    while (lo < hi) { int mid = (lo + hi) >> 1; if (batch[mid] < g + 1) lo = mid + 1; else hi = mid; }
    int end = lo;

    float s = 0.f, m = -3.4e38f;
    for (int i = start + w; i < end; i += 4) {
        float v = __half2float(h[(size_t)i * 64 + c]);
        s += v;
        m = fmaxf(m, v);
    }
    psum[w][c] = s;
    pmax[w][c] = m;
    __syncthreads();
    if (w == 0) {
        float ss = psum[0][c] + psum[1][c] + psum[2][c] + psum[3][c];
        float mm = fmaxf(fmaxf(pmax[0][c], pmax[1][c]), fmaxf(pmax[2][c], pmax[3][c]));
        int cnt = end - start;
        pool[c] = ss / fmaxf((float)cnt, 1.f);
        pool[64 + c] = (cnt > 0) ? mm : 0.f;
    }
    __syncthreads();
    if (t < 64) {
        float z = bc1[t];
#pragma unroll 8
        for (int k = 0; k < 128; ++k) z = fmaf(pool[k], Wc1[k * 64 + t], z);
        hid[t] = fmaxf(z, 0.f);
    }
    __syncthreads();
    if (t < N_CLS) {
        float z = bc2[t];
#pragma unroll
        for (int k = 0; k < 64; ++k) z = fmaf(hid[k], Wc2[k * N_CLS + t], z);
        out[g * N_CLS + t] = z;
    }
}

extern "C" void kernel_launch(void* const* d_in, const int* in_sizes, int n_in,
                              void* d_out, int out_size, void* d_ws, size_t ws_size,
                              hipStream_t stream) {
    const float* x     = (const float*)d_in[0];
    const int*   ei    = (const int*)d_in[1];
    const float* ea    = (const float*)d_in[2];
    const int*   batch = (const int*)d_in[3];
    const float* We1 = (const float*)d_in[4],  *be1 = (const float*)d_in[5];
    const float* We2 = (const float*)d_in[6],  *be2 = (const float*)d_in[7];
    const float* We3 = (const float*)d_in[8],  *be3 = (const float*)d_in[9];
    const float* W1 = (const float*)d_in[10], *b1 = (const float*)d_in[11];
    const float* g1 = (const float*)d_in[12], *bt1 = (const float*)d_in[13];
    const float* rm1 = (const float*)d_in[14], *rv1 = (const float*)d_in[15];
    const float* W2 = (const float*)d_in[16], *b2 = (const float*)d_in[17];
    const float* g2 = (const float*)d_in[18], *bt2 = (const float*)d_in[19];
    const float* rm2 = (const float*)d_in[20], *rv2 = (const float*)d_in[21];
    const float* W3 = (const float*)d_in[22], *b3 = (const float*)d_in[23];
    const float* g3 = (const float*)d_in[24], *bt3 = (const float*)d_in[25];
    const float* rm3 = (const float*)d_in[26], *rv3 = (const float*)d_in[27];
    const float* Wr = (const float*)d_in[28], *br = (const float*)d_in[29];
    const float* Wc1 = (const float*)d_in[30], *bc1 = (const float*)d_in[31];
    const float* Wc2 = (const float*)d_in[32], *bc2 = (const float*)d_in[33];

    // workspace layout
    int* deg    = (int*)d_ws;                   // N
    int* off    = deg + N_NODES;                // N+4
    int* cursor = off + (N_NODES + 4);          // N
    int* bsum   = cursor + N_NODES;             // 256
    int* bcur   = bsum + 256;                   // 1024 (NB=1000, padded)
    int4* edges = (int4*)(bcur + 1024);         // E * 16B
    int4* stage = edges + E_EDGES;              // E * 16B
    __half* hA  = (__half*)(stage + E_EDGES);   // N*64 fp16
    __half* hB  = hA + (size_t)N_NODES * 64;    // N*64 fp16
    __half* x16 = hB + (size_t)N_NODES * 64;    // N*16 fp16

    hipMemsetAsync(deg, 0, N_NODES * sizeof(int), stream);

    const int* src = ei;
    const int* dst = ei + E_EDGES;

    k_pack_x<<<N_NODES * 16 / 256, 256, 0, stream>>>(x, x16);
    k_hist<<<E_EDGES / 256, 256, 0, stream>>>(dst, deg);
    k_scan1<<<N_NODES / 1024, 256, 0, stream>>>(deg, bsum);
    k_scan_top<<<1, 256, 0, stream>>>(bsum, N_NODES / 1024);
    k_scan_down<<<N_NODES / 1024, 256, 0, stream>>>(deg, bsum, off, cursor);
    k_init_bcur<<<(NB + 255) / 256, 256, 0, stream>>>(off, bcur);
    k_bin<<<E_EDGES / TILE, 256, 0, stream>>>(src, dst, (const float2*)ea, bcur, stage);
    k_final<<<NB, 256, 0, stream>>>(off, stage, cursor, edges);

    const int gine_blocks = N_NODES / 4;  // one node per wave, 4 waves/block
    k_gine12<<<gine_blocks, 256, 0, stream>>>(x, x16, hA, off, edges,
                                              We1, be1, W1, b1, g1, bt1, rm1, rv1, Wr, br);
    k_gine64<<<gine_blocks, 256, 0, stream>>>(hA, hB, off, edges,
                                              We2, be2, W2, b2, g2, bt2, rm2, rv2);
    k_gine64<<<gine_blocks, 256, 0, stream>>>(hB, hA, off, edges,
                                              We3, be3, W3, b3, g3, bt3, rm3, rv3);
    k_pool<<<G_GRAPHS, 256, 0, stream>>>(hA, batch, Wc1, bc1, Wc2, bc2, (float*)d_out);
}

// Round 9
// 630.303 us; speedup vs baseline: 1.1760x; 1.1760x over previous
//
#include <hip/hip_runtime.h>
#include <hip/hip_bf16.h>
#include <hip/hip_fp16.h>

#define N_NODES 128000
#define E_EDGES 2048000
#define G_GRAPHS 512
#define D_IN 12
#define D_H 64
#define N_CLS 10
#define BN_EPS 1e-5f
#define NB 1000        // buckets = dst >> 7 (128-node ranges)
#define TILE 8192      // edges per k_bin block (250 blocks)

// ---------------- CSR build ----------------

__global__ __launch_bounds__(256) void k_hist(const int* __restrict__ dst, int* __restrict__ deg) {
    int e = blockIdx.x * 256 + threadIdx.x;
    if (e < E_EDGES) atomicAdd(&deg[dst[e]], 1);
}

__global__ __launch_bounds__(256) void k_scan1(const int* __restrict__ deg, int* __restrict__ bsum) {
    __shared__ int sm[256];
    int t = threadIdx.x;
    int base = blockIdx.x * 1024 + t * 4;
    int s = deg[base] + deg[base + 1] + deg[base + 2] + deg[base + 3];
    sm[t] = s;
    __syncthreads();
    for (int off = 128; off > 0; off >>= 1) {
        if (t < off) sm[t] += sm[t + off];
        __syncthreads();
    }
    if (t == 0) bsum[blockIdx.x] = sm[0];
}

__global__ __launch_bounds__(256) void k_scan_top(int* __restrict__ bsum, int nb) {
    __shared__ int sm[256];
    int t = threadIdx.x;
    int v = (t < nb) ? bsum[t] : 0;
    sm[t] = v;
    __syncthreads();
    for (int off = 1; off < 256; off <<= 1) {
        int x = 0;
        if (t >= off) x = sm[t - off];
        __syncthreads();
        sm[t] += x;
        __syncthreads();
    }
    if (t < nb) bsum[t] = sm[t] - v;  // exclusive
}

__global__ __launch_bounds__(256) void k_scan_down(const int* __restrict__ deg, const int* __restrict__ bsum,
                                                   int* __restrict__ offsets, int* __restrict__ cursor) {
    __shared__ int sm[256];
    int t = threadIdx.x;
    int blk = blockIdx.x;
    int base = blk * 1024 + t * 4;
    int d0 = deg[base], d1 = deg[base + 1], d2 = deg[base + 2], d3 = deg[base + 3];
    int s = d0 + d1 + d2 + d3;
    sm[t] = s;
    __syncthreads();
    for (int off = 1; off < 256; off <<= 1) {
        int x = 0;
        if (t >= off) x = sm[t - off];
        __syncthreads();
        sm[t] += x;
        __syncthreads();
    }
    int tbase = bsum[blk] + sm[t] - s;
    int p0 = tbase, p1 = tbase + d0, p2 = p1 + d1, p3 = p2 + d2;
    offsets[base] = p0;     cursor[base] = p0;
    offsets[base + 1] = p1; cursor[base + 1] = p1;
    offsets[base + 2] = p2; cursor[base + 2] = p2;
    offsets[base + 3] = p3; cursor[base + 3] = p3;
    if (blk == 0 && t == 0) offsets[N_NODES] = E_EDGES;
}

__global__ __launch_bounds__(256) void k_init_bcur(const int* __restrict__ offsets, int* __restrict__ bcur) {
    int b = blockIdx.x * 256 + threadIdx.x;
    if (b < NB) bcur[b] = offsets[b * 128];
}

// Phase 1: LDS-ranked binning into per-bucket contiguous runs (coalesced-ish writes)
__global__ __launch_bounds__(256) void k_bin(const int* __restrict__ src, const int* __restrict__ dst,
                                             const float2* __restrict__ attr, int* __restrict__ bcur,
                                             int4* __restrict__ stage) {
    __shared__ int hist[NB];
    __shared__ int base_s[NB];
    __shared__ int rk[TILE];  // packed bucket(10) << 13 | rank(13)
    const int t = threadIdx.x;
    const int e0 = blockIdx.x * TILE;
    for (int i = t; i < NB; i += 256) hist[i] = 0;
    __syncthreads();
    for (int i = t; i < TILE; i += 256) {
        int d = dst[e0 + i];
        int b = d >> 7;
        int r = atomicAdd(&hist[b], 1);
        rk[i] = (b << 13) | r;
    }
    __syncthreads();
    for (int i = t; i < NB; i += 256) {
        int cb = hist[i];
        base_s[i] = (cb > 0) ? atomicAdd(&bcur[i], cb) : 0;
    }
    __syncthreads();
    for (int i = t; i < TILE; i += 256) {
        int pr = rk[i];
        int b = pr >> 13, r = pr & 8191;
        float2 a = attr[e0 + i];
        stage[base_s[b] + r] = make_int4(src[e0 + i], __float_as_int(a.x), __float_as_int(a.y), dst[e0 + i]);
    }
}

// Phase 2: one block per bucket; exact CSR placement; pack record to 8B (src + fp16x2 attrs)
__global__ __launch_bounds__(256) void k_final(const int* __restrict__ offsets, const int4* __restrict__ stage,
                                               int* __restrict__ cursor, int2* __restrict__ edges) {
    const int b = blockIdx.x;
    const int s0 = offsets[b * 128];
    const int s1 = offsets[(b + 1) * 128];
    for (int i = s0 + threadIdx.x; i < s1; i += 256) {
        int4 r = stage[i];
        int p = atomicAdd(&cursor[r.w], 1);
        __half2 hp;
        hp.x = __float2half(__int_as_float(r.y));
        hp.y = __float2half(__int_as_float(r.z));
        edges[p] = make_int2(r.x, *(int*)&hp);
    }
}

// ---------------- Layer 1 (12-dim input, 64-dim output, fp16 out) ----------------
// Round-6-proven gather: fp32 x, float hv, 8-burst + scalar tail.
__global__ __launch_bounds__(256) void k_gine12(
    const float* __restrict__ x, __half* __restrict__ hout,
    const int* __restrict__ off, const int2* __restrict__ edges,
    const float* __restrict__ We1, const float* __restrict__ be1,
    const float* __restrict__ W1, const float* __restrict__ b1,
    const float* __restrict__ g1, const float* __restrict__ bt1,
    const float* __restrict__ rm1, const float* __restrict__ rv1,
    const float* __restrict__ Wr, const float* __restrict__ br) {
    __shared__ float W1lds[D_IN * 64];
    __shared__ float Wrlds[D_IN * 64];
    __shared__ float u_lds[4][D_IN];
    __shared__ float x_lds[4][D_IN];
    const int t = threadIdx.x, w = t >> 6, c = t & 63;
    for (int i = t; i < D_IN * 64; i += 256) {
        W1lds[i] = W1[i];
        Wrlds[i] = Wr[i];
    }
    float we0 = 0.f, we1 = 0.f, bec = 0.f;
    if (c < D_IN) { we0 = We1[c]; we1 = We1[D_IN + c]; bec = be1[c]; }
    const float sj = g1[c] * rsqrtf(rv1[c] + BN_EPS);
    const float cj = (b1[c] - rm1[c]) * sj + bt1[c];
    const float brj = br[c];
    __syncthreads();

    const int n = blockIdx.x * 4 + w;
    const int rs = off[n], re = off[n + 1];
    float acc = 0.f;
    for (int base = rs; base < re; base += 64) {
        const int cnt = min(64, re - base);
        int2 rec = make_int2(0, 0);
        if (c < cnt) rec = edges[base + c];  // one coalesced wave-wide record load
        const int full = cnt & ~7;
        for (int j = 0; j < full; j += 8) {
            float hv[8], axv[8], ayv[8];
#pragma unroll
            for (int u = 0; u < 8; ++u) {
                int s = __builtin_amdgcn_readlane(rec.x, j + u);
                int pk = __builtin_amdgcn_readlane(rec.y, j + u);
                __half2 h2 = *(__half2*)&pk;
                float2 a = __half22float2(h2);
                axv[u] = a.x; ayv[u] = a.y;
                hv[u] = (c < D_IN) ? x[(size_t)s * D_IN + c] : 0.f;
            }
#pragma unroll
            for (int u = 0; u < 8; ++u)
                acc += fmaxf(hv[u] + fmaf(axv[u], we0, fmaf(ayv[u], we1, bec)), 0.f);
        }
        for (int j = full; j < cnt; ++j) {
            int s = __builtin_amdgcn_readlane(rec.x, j);
            int pk = __builtin_amdgcn_readlane(rec.y, j);
            __half2 h2 = *(__half2*)&pk;
            float2 a = __half22float2(h2);
            float xs = (c < D_IN) ? x[(size_t)s * D_IN + c] : 0.f;
            acc += fmaxf(xs + fmaf(a.x, we0, fmaf(a.y, we1, bec)), 0.f);
        }
    }
    if (c < D_IN) {
        float xc = x[(size_t)n * D_IN + c];
        x_lds[w][c] = xc;
        u_lds[w][c] = xc + acc;
    }
    float z = 0.f, r = 0.f;
#pragma unroll
    for (int k = 0; k < D_IN; ++k) {
        z = fmaf(u_lds[w][k], W1lds[k * 64 + c], z);
        r = fmaf(x_lds[w][k], Wrlds[k * 64 + c], r);
    }
    hout[(size_t)n * 64 + c] = __float2half(fmaxf(fmaf(z, sj, cj), 0.f) + r + brj);
}

// ---------------- Layers 2/3 (64-dim, fp16 h storage) ----------------
// Round-8 structure: 16-burst with clamped index (dup loads hit L1), no ternary.
__global__ __launch_bounds__(256) void k_gine64(
    const __half* __restrict__ hin, __half* __restrict__ hout,
    const int* __restrict__ off, const int2* __restrict__ edges,
    const float* __restrict__ We, const float* __restrict__ be,
    const float* __restrict__ W, const float* __restrict__ b,
    const float* __restrict__ g, const float* __restrict__ bt,
    const float* __restrict__ rm, const float* __restrict__ rv) {
    __shared__ float Wlds[64 * 64];
    __shared__ float u_lds[4][64];
    const int t = threadIdx.x, w = t >> 6, c = t & 63;
    {
        const float4* W4 = (const float4*)W;
        float4* Wl4 = (float4*)Wlds;
#pragma unroll
        for (int i = t; i < 1024; i += 256) Wl4[i] = W4[i];
    }
    const float we0 = We[c], we1 = We[64 + c], bec = be[c];
    const float sj = g[c] * rsqrtf(rv[c] + BN_EPS);
    const float cj = (b[c] - rm[c]) * sj + bt[c];
    __syncthreads();

    const int n = blockIdx.x * 4 + w;
    const int rs = off[n], re = off[n + 1];
    const __half hc16 = hin[(size_t)n * 64 + c];  // hoisted center load
    float acc = 0.f;
    for (int base = rs; base < re; base += 64) {
        const int cnt = min(64, re - base);
        int2 rec = make_int2(0, 0);
        if (c < cnt) rec = edges[base + c];  // one coalesced wave-wide record load
        for (int j = 0; j < cnt; j += 16) {
            __half hv[16];
#pragma unroll
            for (int u = 0; u < 16; ++u) {
                int idx = j + u; if (idx > cnt - 1) idx = cnt - 1;  // clamp: dup loads hit L1
                int s = __builtin_amdgcn_readlane(rec.x, idx);
                hv[u] = hin[(size_t)s * 64 + c];  // 16 gathers in flight
            }
#pragma unroll
            for (int u = 0; u < 16; ++u) {
                if (j + u < cnt) {
                    int pk = __builtin_amdgcn_readlane(rec.y, j + u);
                    __half2 h2 = *(__half2*)&pk;
                    float2 a = __half22float2(h2);
                    acc += fmaxf(__half2float(hv[u]) + fmaf(a.x, we0, fmaf(a.y, we1, bec)), 0.f);
                }
            }
        }
    }
    const float hc = __half2float(hc16);
    u_lds[w][c] = hc + acc;
    float z = 0.f;
    const float4* u4 = (const float4*)u_lds[w];
#pragma unroll
    for (int k4 = 0; k4 < 16; ++k4) {
        float4 uu = u4[k4];
        z = fmaf(uu.x, Wlds[(k4 * 4 + 0) * 64 + c], z);
        z = fmaf(uu.y, Wlds[(k4 * 4 + 1) * 64 + c], z);
        z = fmaf(uu.z, Wlds[(k4 * 4 + 2) * 64 + c], z);
        z = fmaf(uu.w, Wlds[(k4 * 4 + 3) * 64 + c], z);
    }
    hout[(size_t)n * 64 + c] = __float2half(fmaxf(fmaf(z, sj, cj), 0.f) + hc);
}

// ---------------- Pool (mean+max per graph) + classifier ----------------
__global__ __launch_bounds__(256) void k_pool(
    const __half* __restrict__ h, const int* __restrict__ batch,
    const float* __restrict__ Wc1, const float* __restrict__ bc1,
    const float* __restrict__ Wc2, const float* __restrict__ bc2,
    float* __restrict__ out) {
    __shared__ float psum[4][64];
    __shared__ float pmax[4][64];
    __shared__ float pool[128];
    __shared__ float hid[64];
    const int t = threadIdx.x, w = t >> 6, c = t & 63;
    const int g = blockIdx.x;
    int lo = 0, hi = N_NODES;
    while (lo < hi) { int mid = (lo + hi) >> 1; if (batch[mid] < g) lo = mid + 1; else hi = mid; }
    int start = lo;
    hi = N_NODES;
    while (lo < hi) { int mid = (lo + hi) >> 1; if (batch[mid] < g + 1) lo = mid + 1; else hi = mid; }
    int end = lo;

    float s = 0.f, m = -3.4e38f;
    for (int i = start + w; i < end; i += 4) {
        float v = __half2float(h[(size_t)i * 64 + c]);
        s += v;
        m = fmaxf(m, v);
    }
    psum[w][c] = s;
    pmax[w][c] = m;
    __syncthreads();
    if (w == 0) {
        float ss = psum[0][c] + psum[1][c] + psum[2][c] + psum[3][c];
        float mm = fmaxf(fmaxf(pmax[0][c], pmax[1][c]), fmaxf(pmax[2][c], pmax[3][c]));
        int cnt = end - start;
        pool[c] = ss / fmaxf((float)cnt, 1.f);
        pool[64 + c] = (cnt > 0) ? mm : 0.f;
    }
    __syncthreads();
    if (t < 64) {
        float z = bc1[t];
#pragma unroll 8
        for (int k = 0; k < 128; ++k) z = fmaf(pool[k], Wc1[k * 64 + t], z);
        hid[t] = fmaxf(z, 0.f);
    }
    __syncthreads();
    if (t < N_CLS) {
        float z = bc2[t];
#pragma unroll
        for (int k = 0; k < 64; ++k) z = fmaf(hid[k], Wc2[k * N_CLS + t], z);
        out[g * N_CLS + t] = z;
    }
}

extern "C" void kernel_launch(void* const* d_in, const int* in_sizes, int n_in,
                              void* d_out, int out_size, void* d_ws, size_t ws_size,
                              hipStream_t stream) {
    const float* x     = (const float*)d_in[0];
    const int*   ei    = (const int*)d_in[1];
    const float* ea    = (const float*)d_in[2];
    const int*   batch = (const int*)d_in[3];
    const float* We1 = (const float*)d_in[4],  *be1 = (const float*)d_in[5];
    const float* We2 = (const float*)d_in[6],  *be2 = (const float*)d_in[7];
    const float* We3 = (const float*)d_in[8],  *be3 = (const float*)d_in[9];
    const float* W1 = (const float*)d_in[10], *b1 = (const float*)d_in[11];
    const float* g1 = (const float*)d_in[12], *bt1 = (const float*)d_in[13];
    const float* rm1 = (const float*)d_in[14], *rv1 = (const float*)d_in[15];
    const float* W2 = (const float*)d_in[16], *b2 = (const float*)d_in[17];
    const float* g2 = (const float*)d_in[18], *bt2 = (const float*)d_in[19];
    const float* rm2 = (const float*)d_in[20], *rv2 = (const float*)d_in[21];
    const float* W3 = (const float*)d_in[22], *b3 = (const float*)d_in[23];
    const float* g3 = (const float*)d_in[24], *bt3 = (const float*)d_in[25];
    const float* rm3 = (const float*)d_in[26], *rv3 = (const float*)d_in[27];
    const float* Wr = (const float*)d_in[28], *br = (const float*)d_in[29];
    const float* Wc1 = (const float*)d_in[30], *bc1 = (const float*)d_in[31];
    const float* Wc2 = (const float*)d_in[32], *bc2 = (const float*)d_in[33];

    // workspace layout (int header = 385284 ints = 1541136 B, 16B-divisible)
    int* deg    = (int*)d_ws;                   // N
    int* off    = deg + N_NODES;                // N+4
    int* cursor = off + (N_NODES + 4);          // N
    int* bsum   = cursor + N_NODES;             // 256
    int* bcur   = bsum + 256;                   // 1024 (NB=1000, padded)
    int2* edges = (int2*)(bcur + 1024);         // E * 8B packed records
    int4* stage = (int4*)(edges + E_EDGES);     // E * 16B
    __half* hA  = (__half*)(stage + E_EDGES);   // N*64 fp16
    __half* hB  = hA + (size_t)N_NODES * 64;    // N*64 fp16

    hipMemsetAsync(deg, 0, N_NODES * sizeof(int), stream);

    const int* src = ei;
    const int* dst = ei + E_EDGES;

    k_hist<<<E_EDGES / 256, 256, 0, stream>>>(dst, deg);
    k_scan1<<<N_NODES / 1024, 256, 0, stream>>>(deg, bsum);
    k_scan_top<<<1, 256, 0, stream>>>(bsum, N_NODES / 1024);
    k_scan_down<<<N_NODES / 1024, 256, 0, stream>>>(deg, bsum, off, cursor);
    k_init_bcur<<<(NB + 255) / 256, 256, 0, stream>>>(off, bcur);
    k_bin<<<E_EDGES / TILE, 256, 0, stream>>>(src, dst, (const float2*)ea, bcur, stage);
    k_final<<<NB, 256, 0, stream>>>(off, stage, cursor, edges);

    const int gine_blocks = N_NODES / 4;  // one node per wave, 4 waves/block
    k_gine12<<<gine_blocks, 256, 0, stream>>>(x, hA, off, edges,
                                              We1, be1, W1, b1, g1, bt1, rm1, rv1, Wr, br);
    k_gine64<<<gine_blocks, 256, 0, stream>>>(hA, hB, off, edges,
                                              We2, be2, W2, b2, g2, bt2, rm2, rv2);
    k_gine64<<<gine_blocks, 256, 0, stream>>>(hB, hA, off, edges,
                                              We3, be3, W3, b3, g3, bt3, rm3, rv3);
    k_pool<<<G_GRAPHS, 256, 0, stream>>>(hA, batch, Wc1, bc1, Wc2, bc2, (float*)d_out);
}

// Round 10
// 527.028 us; speedup vs baseline: 1.4064x; 1.1960x over previous
//
#include <hip/hip_runtime.h>
#include <hip/hip_bf16.h>
#include <hip/hip_fp16.h>

#define N_NODES 128000
#define E_EDGES 2048000
#define G_GRAPHS 512
#define D_IN 12
#define D_H 64
#define N_CLS 10
#define BN_EPS 1e-5f
#define NB 1000        // buckets = dst >> 7 (128-node ranges)
#define BCAP 2560      // fixed records per bucket region (mean 2048, sd 45 -> 11 sigma)
#define TILE 8192      // edges per k_bin block (250 blocks)

typedef _Float16 h2vec __attribute__((ext_vector_type(2)));

// ---------------- CSR build: bucket counting-sort ----------------

// Phase 1: LDS-ranked binning into fixed per-bucket regions (no global scan dependency)
__global__ __launch_bounds__(256) void k_bin(const int* __restrict__ src, const int* __restrict__ dst,
                                             const float2* __restrict__ attr, int* __restrict__ gcount,
                                             int2* __restrict__ stage) {
    __shared__ int hist[NB];
    __shared__ int base_s[NB];
    __shared__ int rk[TILE];  // packed b(10)<<20 | dstLow(7)<<13 | rank(13)
    const int t = threadIdx.x;
    const int e0 = blockIdx.x * TILE;
    for (int i = t; i < NB; i += 256) hist[i] = 0;
    __syncthreads();
    for (int i = t; i < TILE; i += 256) {
        int d = dst[e0 + i];
        int b = d >> 7;
        int r = atomicAdd(&hist[b], 1);
        rk[i] = (b << 20) | ((d & 127) << 13) | r;
    }
    __syncthreads();
    for (int i = t; i < NB; i += 256) {
        int cb = hist[i];
        base_s[i] = i * BCAP + ((cb > 0) ? atomicAdd(&gcount[i], cb) : 0);
    }
    __syncthreads();
    for (int i = t; i < TILE; i += 256) {
        int pr = rk[i];
        int b = pr >> 20, dl = (pr >> 13) & 127, r = pr & 8191;
        float2 a = attr[e0 + i];
        __half2 h2 = __floats2half2_rn(a.x, a.y);
        stage[base_s[b] + r] = make_int2(src[e0 + i] | (dl << 17), *(int*)&h2);
    }
}

// Scan 1000 bucket counts -> bucket bases; also writes offsets[N] = E
__global__ __launch_bounds__(256) void k_bscan(const int* __restrict__ gcount, int* __restrict__ bbase,
                                               int* __restrict__ offsets) {
    __shared__ int sm[256];
    const int t = threadIdx.x;
    int c0 = gcount[t * 4], c1 = gcount[t * 4 + 1], c2 = gcount[t * 4 + 2], c3 = gcount[t * 4 + 3];
    int s = c0 + c1 + c2 + c3;
    sm[t] = s;
    __syncthreads();
    for (int off = 1; off < 256; off <<= 1) {
        int x = 0;
        if (t >= off) x = sm[t - off];
        __syncthreads();
        sm[t] += x;
        __syncthreads();
    }
    int base = sm[t] - s;  // exclusive
    if (t * 4 < NB)     bbase[t * 4]     = base;
    if (t * 4 + 1 < NB) bbase[t * 4 + 1] = base + c0;
    if (t * 4 + 2 < NB) bbase[t * 4 + 2] = base + c0 + c1;
    if (t * 4 + 3 < NB) bbase[t * 4 + 3] = base + c0 + c1 + c2;
    if (t == 255) offsets[N_NODES] = sm[255];
}

// Phase 2: one block per bucket. Stage->LDS, per-node counts+scan in LDS, write off + exact CSR.
__global__ __launch_bounds__(256) void k_final(const int* __restrict__ gcount, const int* __restrict__ bbase,
                                               const int2* __restrict__ stage,
                                               int* __restrict__ offsets, int2* __restrict__ edges) {
    __shared__ int2 recs[BCAP];   // 20.5 KB
    __shared__ int cnt[128];      // counts -> cursors
    __shared__ int excl[128];
    const int b = blockIdx.x, t = threadIdx.x;
    const int count = gcount[b];
    const int base = bbase[b];
    if (t < 128) cnt[t] = 0;
    __syncthreads();
    for (int i = t; i < count; i += 256) {
        int2 r = stage[b * BCAP + i];
        recs[i] = r;
        atomicAdd(&cnt[(r.x >> 17) & 127], 1);
    }
    __syncthreads();
    if (t == 0) {
        int s = 0;
        for (int k = 0; k < 128; ++k) { int c = cnt[k]; excl[k] = s; cnt[k] = s; s += c; }
    }
    __syncthreads();
    if (t < 128) offsets[b * 128 + t] = base + excl[t];
    for (int i = t; i < count; i += 256) {
        int2 r = recs[i];
        int dl = (r.x >> 17) & 127;
        int p = atomicAdd(&cnt[dl], 1);
        edges[base + p] = make_int2(r.x & 0x1FFFF, r.y);  // clean src + half2 attrs
    }
}

// ---------------- Layer 1 (12-dim input, 64-dim output, fp16 out) ----------------
__global__ __launch_bounds__(256) void k_gine12(
    const float* __restrict__ x, __half* __restrict__ hout,
    const int* __restrict__ off, const int2* __restrict__ edges,
    const float* __restrict__ We1, const float* __restrict__ be1,
    const float* __restrict__ W1, const float* __restrict__ b1,
    const float* __restrict__ g1, const float* __restrict__ bt1,
    const float* __restrict__ rm1, const float* __restrict__ rv1,
    const float* __restrict__ Wr, const float* __restrict__ br) {
    __shared__ float W1lds[D_IN * 64];
    __shared__ float Wrlds[D_IN * 64];
    __shared__ float u_lds[4][D_IN];
    __shared__ float x_lds[4][D_IN];
    const int t = threadIdx.x, w = t >> 6, c = t & 63;
    for (int i = t; i < D_IN * 64; i += 256) {
        W1lds[i] = W1[i];
        Wrlds[i] = Wr[i];
    }
    h2vec we2 = {(_Float16)0.f, (_Float16)0.f};
    float bec = 0.f;
    if (c < D_IN) { we2[0] = (_Float16)We1[c]; we2[1] = (_Float16)We1[D_IN + c]; bec = be1[c]; }
    const float sj = g1[c] * rsqrtf(rv1[c] + BN_EPS);
    const float cj = (b1[c] - rm1[c]) * sj + bt1[c];
    const float brj = br[c];
    __syncthreads();

    const int n = blockIdx.x * 4 + w;
    const int rs = off[n], re = off[n + 1];
    float acc = 0.f;
    for (int base = rs; base < re; base += 64) {
        const int cnt = min(64, re - base);
        int2 rec = make_int2(0, 0);
        if (c < cnt) rec = edges[base + c];  // one coalesced wave-wide record load
        const int full = cnt & ~7;
        for (int j = 0; j < full; j += 8) {
            float hv[8];
            int pkv[8];
#pragma unroll
            for (int u = 0; u < 8; ++u) {
                int s = __builtin_amdgcn_readlane(rec.x, j + u);
                pkv[u] = __builtin_amdgcn_readlane(rec.y, j + u);
                hv[u] = (c < D_IN) ? x[(size_t)s * D_IN + c] : 0.f;
            }
#pragma unroll
            for (int u = 0; u < 8; ++u) {
                float q = __builtin_amdgcn_fdot2(__builtin_bit_cast(h2vec, pkv[u]), we2, bec, false);
                acc += fmaxf(hv[u] + q, 0.f);
            }
        }
        for (int j = full; j < cnt; ++j) {
            int s = __builtin_amdgcn_readlane(rec.x, j);
            int pk = __builtin_amdgcn_readlane(rec.y, j);
            float xs = (c < D_IN) ? x[(size_t)s * D_IN + c] : 0.f;
            float q = __builtin_amdgcn_fdot2(__builtin_bit_cast(h2vec, pk), we2, bec, false);
            acc += fmaxf(xs + q, 0.f);
        }
    }
    if (c < D_IN) {
        float xc = x[(size_t)n * D_IN + c];
        x_lds[w][c] = xc;
        u_lds[w][c] = xc + acc;
    }
    float z = 0.f, r = 0.f;
#pragma unroll
    for (int k = 0; k < D_IN; ++k) {
        z = fmaf(u_lds[w][k], W1lds[k * 64 + c], z);
        r = fmaf(x_lds[w][k], Wrlds[k * 64 + c], r);
    }
    hout[(size_t)n * 64 + c] = __float2half(fmaxf(fmaf(z, sj, cj), 0.f) + r + brj);
}

// ---------------- Layers 2/3 (64-dim, fp16 h storage) ----------------
__global__ __launch_bounds__(256) void k_gine64(
    const __half* __restrict__ hin, __half* __restrict__ hout,
    const int* __restrict__ off, const int2* __restrict__ edges,
    const float* __restrict__ We, const float* __restrict__ be,
    const float* __restrict__ W, const float* __restrict__ b,
    const float* __restrict__ g, const float* __restrict__ bt,
    const float* __restrict__ rm, const float* __restrict__ rv) {
    __shared__ float Wlds[64 * 64];
    __shared__ float u_lds[4][64];
    const int t = threadIdx.x, w = t >> 6, c = t & 63;
    {
        const float4* W4 = (const float4*)W;
        float4* Wl4 = (float4*)Wlds;
#pragma unroll
        for (int i = t; i < 1024; i += 256) Wl4[i] = W4[i];
    }
    h2vec we2 = {(_Float16)We[c], (_Float16)We[64 + c]};
    const float bec = be[c];
    const float sj = g[c] * rsqrtf(rv[c] + BN_EPS);
    const float cj = (b[c] - rm[c]) * sj + bt[c];
    __syncthreads();

    const int n = blockIdx.x * 4 + w;
    const int rs = off[n], re = off[n + 1];
    const __half hc16 = hin[(size_t)n * 64 + c];  // hoisted center load
    float acc = 0.f;
    for (int base = rs; base < re; base += 64) {
        const int cnt = min(64, re - base);
        int2 rec = make_int2(0, 0);
        if (c < cnt) rec = edges[base + c];  // one coalesced wave-wide record load
        for (int j = 0; j < cnt; j += 16) {
            __half hv[16];
#pragma unroll
            for (int u = 0; u < 16; ++u) {
                int idx = j + u; if (idx > cnt - 1) idx = cnt - 1;  // clamp: dup loads hit L1
                int s = __builtin_amdgcn_readlane(rec.x, idx);
                hv[u] = hin[(size_t)s * 64 + c];  // 16 gathers in flight
            }
#pragma unroll
            for (int u = 0; u < 16; ++u) {
                if (j + u < cnt) {
                    int pk = __builtin_amdgcn_readlane(rec.y, j + u);
                    float q = __builtin_amdgcn_fdot2(__builtin_bit_cast(h2vec, pk), we2, bec, false);
                    acc += fmaxf(__half2float(hv[u]) + q, 0.f);
                }
            }
        }
    }
    const float hc = __half2float(hc16);
    u_lds[w][c] = hc + acc;
    float z = 0.f;
    const float4* u4 = (const float4*)u_lds[w];
#pragma unroll
    for (int k4 = 0; k4 < 16; ++k4) {
        float4 uu = u4[k4];
        z = fmaf(uu.x, Wlds[(k4 * 4 + 0) * 64 + c], z);
        z = fmaf(uu.y, Wlds[(k4 * 4 + 1) * 64 + c], z);
        z = fmaf(uu.z, Wlds[(k4 * 4 + 2) * 64 + c], z);
        z = fmaf(uu.w, Wlds[(k4 * 4 + 3) * 64 + c], z);
    }
    hout[(size_t)n * 64 + c] = __float2half(fmaxf(fmaf(z, sj, cj), 0.f) + hc);
}

// ---------------- Pool (mean+max per graph) + classifier ----------------
__global__ __launch_bounds__(256) void k_pool(
    const __half* __restrict__ h, const int* __restrict__ batch,
    const float* __restrict__ Wc1, const float* __restrict__ bc1,
    const float* __restrict__ Wc2, const float* __restrict__ bc2,
    float* __restrict__ out) {
    __shared__ float psum[4][64];
    __shared__ float pmax[4][64];
    __shared__ float pool[128];
    __shared__ float hid[64];
    const int t = threadIdx.x, w = t >> 6, c = t & 63;
    const int g = blockIdx.x;
    int lo = 0, hi = N_NODES;
    while (lo < hi) { int mid = (lo + hi) >> 1; if (batch[mid] < g) lo = mid + 1; else hi = mid; }
    int start = lo;
    hi = N_NODES;
    while (lo < hi) { int mid = (lo + hi) >> 1; if (batch[mid] < g + 1) lo = mid + 1; else hi = mid; }
    int end = lo;

    float s = 0.f, m = -3.4e38f;
    for (int i = start + w; i < end; i += 4) {
        float v = __half2float(h[(size_t)i * 64 + c]);
        s += v;
        m = fmaxf(m, v);
    }
    psum[w][c] = s;
    pmax[w][c] = m;
    __syncthreads();
    if (w == 0) {
        float ss = psum[0][c] + psum[1][c] + psum[2][c] + psum[3][c];
        float mm = fmaxf(fmaxf(pmax[0][c], pmax[1][c]), fmaxf(pmax[2][c], pmax[3][c]));
        int cnt = end - start;
        pool[c] = ss / fmaxf((float)cnt, 1.f);
        pool[64 + c] = (cnt > 0) ? mm : 0.f;
    }
    __syncthreads();
    if (t < 64) {
        float z = bc1[t];
#pragma unroll 8
        for (int k = 0; k < 128; ++k) z = fmaf(pool[k], Wc1[k * 64 + t], z);
        hid[t] = fmaxf(z, 0.f);
    }
    __syncthreads();
    if (t < N_CLS) {
        float z = bc2[t];
#pragma unroll
        for (int k = 0; k < 64; ++k) z = fmaf(hid[k], Wc2[k * N_CLS + t], z);
        out[g * N_CLS + t] = z;
    }
}

extern "C" void kernel_launch(void* const* d_in, const int* in_sizes, int n_in,
                              void* d_out, int out_size, void* d_ws, size_t ws_size,
                              hipStream_t stream) {
    const float* x     = (const float*)d_in[0];
    const int*   ei    = (const int*)d_in[1];
    const float* ea    = (const float*)d_in[2];
    const int*   batch = (const int*)d_in[3];
    const float* We1 = (const float*)d_in[4],  *be1 = (const float*)d_in[5];
    const float* We2 = (const float*)d_in[6],  *be2 = (const float*)d_in[7];
    const float* We3 = (const float*)d_in[8],  *be3 = (const float*)d_in[9];
    const float* W1 = (const float*)d_in[10], *b1 = (const float*)d_in[11];
    const float* g1 = (const float*)d_in[12], *bt1 = (const float*)d_in[13];
    const float* rm1 = (const float*)d_in[14], *rv1 = (const float*)d_in[15];
    const float* W2 = (const float*)d_in[16], *b2 = (const float*)d_in[17];
    const float* g2 = (const float*)d_in[18], *bt2 = (const float*)d_in[19];
    const float* rm2 = (const float*)d_in[20], *rv2 = (const float*)d_in[21];
    const float* W3 = (const float*)d_in[22], *b3 = (const float*)d_in[23];
    const float* g3 = (const float*)d_in[24], *bt3 = (const float*)d_in[25];
    const float* rm3 = (const float*)d_in[26], *rv3 = (const float*)d_in[27];
    const float* Wr = (const float*)d_in[28], *br = (const float*)d_in[29];
    const float* Wc1 = (const float*)d_in[30], *bc1 = (const float*)d_in[31];
    const float* Wc2 = (const float*)d_in[32], *bc2 = (const float*)d_in[33];

    // workspace layout (int header = 128004+1024+1024 = 130052 ints = 520208 B, 16B-divisible)
    int* off    = (int*)d_ws;                   // N+4
    int* gcount = off + (N_NODES + 4);          // 1024 (NB=1000, zero-padded)
    int* bbase  = gcount + 1024;                // 1024
    int2* edges = (int2*)(bbase + 1024);        // E * 8B packed records
    int2* stage = edges + E_EDGES;              // NB*BCAP * 8B fixed bucket regions
    __half* hA  = (__half*)(stage + (size_t)NB * BCAP);  // N*64 fp16
    __half* hB  = hA + (size_t)N_NODES * 64;    // N*64 fp16

    hipMemsetAsync(gcount, 0, 1024 * sizeof(int), stream);

    const int* src = ei;
    const int* dst = ei + E_EDGES;

    k_bin<<<E_EDGES / TILE, 256, 0, stream>>>(src, dst, (const float2*)ea, gcount, stage);
    k_bscan<<<1, 256, 0, stream>>>(gcount, bbase, off);
    k_final<<<NB, 256, 0, stream>>>(gcount, bbase, stage, off, edges);

    const int gine_blocks = N_NODES / 4;  // one node per wave, 4 waves/block
    k_gine12<<<gine_blocks, 256, 0, stream>>>(x, hA, off, edges,
                                              We1, be1, W1, b1, g1, bt1, rm1, rv1, Wr, br);
    k_gine64<<<gine_blocks, 256, 0, stream>>>(hA, hB, off, edges,
                                              We2, be2, W2, b2, g2, bt2, rm2, rv2);
    k_gine64<<<gine_blocks, 256, 0, stream>>>(hB, hA, off, edges,
                                              We3, be3, W3, b3, g3, bt3, rm3, rv3);
    k_pool<<<G_GRAPHS, 256, 0, stream>>>(hA, batch, Wc1, bc1, Wc2, bc2, (float*)d_out);
}

// Round 11
// 508.224 us; speedup vs baseline: 1.4585x; 1.0370x over previous
//
#include <hip/hip_runtime.h>
#include <hip/hip_bf16.h>
#include <hip/hip_fp16.h>

#define N_NODES 128000
#define E_EDGES 2048000
#define G_GRAPHS 512
#define D_IN 12
#define D_H 64
#define N_CLS 10
#define BN_EPS 1e-5f
#define NB 1000        // buckets = dst >> 7 (128-node ranges)
#define BCAP 2560      // fixed records per bucket region (mean 2048, sd 45 -> 11 sigma)
#define TILE 8192      // edges per k_bin block (250 blocks)

typedef _Float16 h2vec __attribute__((ext_vector_type(2)));
typedef _Float16 h4vec __attribute__((ext_vector_type(4)));

// ---------------- CSR build: bucket counting-sort ----------------

__global__ __launch_bounds__(256) void k_bin(const int* __restrict__ src, const int* __restrict__ dst,
                                             const float2* __restrict__ attr, int* __restrict__ gcount,
                                             int2* __restrict__ stage) {
    __shared__ int hist[NB];
    __shared__ int base_s[NB];
    __shared__ int rk[TILE];  // packed b(10)<<20 | dstLow(7)<<13 | rank(13)
    const int t = threadIdx.x;
    const int e0 = blockIdx.x * TILE;
    for (int i = t; i < NB; i += 256) hist[i] = 0;
    __syncthreads();
    for (int i = t; i < TILE; i += 256) {
        int d = dst[e0 + i];
        int b = d >> 7;
        int r = atomicAdd(&hist[b], 1);
        rk[i] = (b << 20) | ((d & 127) << 13) | r;
    }
    __syncthreads();
    for (int i = t; i < NB; i += 256) {
        int cb = hist[i];
        base_s[i] = i * BCAP + ((cb > 0) ? atomicAdd(&gcount[i], cb) : 0);
    }
    __syncthreads();
    for (int i = t; i < TILE; i += 256) {
        int pr = rk[i];
        int b = pr >> 20, dl = (pr >> 13) & 127, r = pr & 8191;
        float2 a = attr[e0 + i];
        __half2 h2 = __floats2half2_rn(a.x, a.y);
        stage[base_s[b] + r] = make_int2(src[e0 + i] | (dl << 17), *(int*)&h2);
    }
}

__global__ __launch_bounds__(256) void k_bscan(const int* __restrict__ gcount, int* __restrict__ bbase,
                                               int* __restrict__ offsets) {
    __shared__ int sm[256];
    const int t = threadIdx.x;
    int c0 = gcount[t * 4], c1 = gcount[t * 4 + 1], c2 = gcount[t * 4 + 2], c3 = gcount[t * 4 + 3];
    int s = c0 + c1 + c2 + c3;
    sm[t] = s;
    __syncthreads();
    for (int off = 1; off < 256; off <<= 1) {
        int x = 0;
        if (t >= off) x = sm[t - off];
        __syncthreads();
        sm[t] += x;
        __syncthreads();
    }
    int base = sm[t] - s;  // exclusive
    if (t * 4 < NB)     bbase[t * 4]     = base;
    if (t * 4 + 1 < NB) bbase[t * 4 + 1] = base + c0;
    if (t * 4 + 2 < NB) bbase[t * 4 + 2] = base + c0 + c1;
    if (t * 4 + 3 < NB) bbase[t * 4 + 3] = base + c0 + c1 + c2;
    if (t == 255) offsets[N_NODES] = sm[255];
}

__global__ __launch_bounds__(256) void k_final(const int* __restrict__ gcount, const int* __restrict__ bbase,
                                               const int2* __restrict__ stage,
                                               int* __restrict__ offsets, int2* __restrict__ edges) {
    __shared__ int2 recs[BCAP];   // 20.5 KB
    __shared__ int cnt[128];
    __shared__ int excl[128];
    const int b = blockIdx.x, t = threadIdx.x;
    const int count = gcount[b];
    const int base = bbase[b];
    if (t < 128) cnt[t] = 0;
    __syncthreads();
    for (int i = t; i < count; i += 256) {
        int2 r = stage[b * BCAP + i];
        recs[i] = r;
        atomicAdd(&cnt[(r.x >> 17) & 127], 1);
    }
    __syncthreads();
    if (t == 0) {
        int s = 0;
        for (int k = 0; k < 128; ++k) { int c = cnt[k]; excl[k] = s; cnt[k] = s; s += c; }
    }
    __syncthreads();
    if (t < 128) offsets[b * 128 + t] = base + excl[t];
    for (int i = t; i < count; i += 256) {
        int2 r = recs[i];
        int dl = (r.x >> 17) & 127;
        int p = atomicAdd(&cnt[dl], 1);
        edges[base + p] = make_int2(r.x & 0x1FFFF, r.y);
    }
}

// ---------------- Layer 1 (12-dim input, 64-dim output, fp16 out) ----------------
__global__ __launch_bounds__(256) void k_gine12(
    const float* __restrict__ x, __half* __restrict__ hout,
    const int* __restrict__ off, const int2* __restrict__ edges,
    const float* __restrict__ We1, const float* __restrict__ be1,
    const float* __restrict__ W1, const float* __restrict__ b1,
    const float* __restrict__ g1, const float* __restrict__ bt1,
    const float* __restrict__ rm1, const float* __restrict__ rv1,
    const float* __restrict__ Wr, const float* __restrict__ br) {
    __shared__ float W1lds[D_IN * 64];
    __shared__ float Wrlds[D_IN * 64];
    __shared__ float u_lds[4][D_IN];
    __shared__ float x_lds[4][D_IN];
    const int t = threadIdx.x, w = t >> 6, c = t & 63;
    for (int i = t; i < D_IN * 64; i += 256) {
        W1lds[i] = W1[i];
        Wrlds[i] = Wr[i];
    }
    h2vec we2 = {(_Float16)0.f, (_Float16)0.f};
    float bec = 0.f;
    if (c < D_IN) { we2[0] = (_Float16)We1[c]; we2[1] = (_Float16)We1[D_IN + c]; bec = be1[c]; }
    const float sj = g1[c] * rsqrtf(rv1[c] + BN_EPS);
    const float cj = (b1[c] - rm1[c]) * sj + bt1[c];
    const float brj = br[c];
    __syncthreads();

    const int n = blockIdx.x * 4 + w;
    const int rs = off[n], re = off[n + 1];
    float acc = 0.f;
    for (int base = rs; base < re; base += 64) {
        const int cnt = min(64, re - base);
        int2 rec = make_int2(0, 0);
        if (c < cnt) rec = edges[base + c];
        const int full = cnt & ~7;
        for (int j = 0; j < full; j += 8) {
            float hv[8];
            int pkv[8];
#pragma unroll
            for (int u = 0; u < 8; ++u) {
                int s = __builtin_amdgcn_readlane(rec.x, j + u);
                pkv[u] = __builtin_amdgcn_readlane(rec.y, j + u);
                hv[u] = (c < D_IN) ? x[(size_t)s * D_IN + c] : 0.f;
            }
#pragma unroll
            for (int u = 0; u < 8; ++u) {
                float q = __builtin_amdgcn_fdot2(__builtin_bit_cast(h2vec, pkv[u]), we2, bec, false);
                acc += fmaxf(hv[u] + q, 0.f);
            }
        }
        for (int j = full; j < cnt; ++j) {
            int s = __builtin_amdgcn_readlane(rec.x, j);
            int pk = __builtin_amdgcn_readlane(rec.y, j);
            float xs = (c < D_IN) ? x[(size_t)s * D_IN + c] : 0.f;
            float q = __builtin_amdgcn_fdot2(__builtin_bit_cast(h2vec, pk), we2, bec, false);
            acc += fmaxf(xs + q, 0.f);
        }
    }
    if (c < D_IN) {
        float xc = x[(size_t)n * D_IN + c];
        x_lds[w][c] = xc;
        u_lds[w][c] = xc + acc;
    }
    float z = 0.f, r = 0.f;
#pragma unroll
    for (int k = 0; k < D_IN; ++k) {
        z = fmaf(u_lds[w][k], W1lds[k * 64 + c], z);
        r = fmaf(x_lds[w][k], Wrlds[k * 64 + c], r);
    }
    hout[(size_t)n * 64 + c] = __float2half(fmaxf(fmaf(z, sj, cj), 0.f) + r + brj);
}

// ---------------- Layers 2/3 (64-dim, fp16 h storage) ----------------
// Packed-fp16 pair consume + fp16 dot2 epilogue with transposed W in LDS.
__global__ __launch_bounds__(256) void k_gine64(
    const __half* __restrict__ hin, __half* __restrict__ hout,
    const int* __restrict__ off, const int2* __restrict__ edges,
    const float* __restrict__ We, const float* __restrict__ be,
    const float* __restrict__ W, const float* __restrict__ b,
    const float* __restrict__ g, const float* __restrict__ bt,
    const float* __restrict__ rm, const float* __restrict__ rv) {
    __shared__ _Float16 WtL[64][68];   // transposed W, fp16, pad 68 -> ~2-way (free) bank aliasing
    __shared__ _Float16 uL[4][64];
    const int t = threadIdx.x, w = t >> 6, c = t & 63;
    for (int i = t; i < 4096; i += 256) {
        int k = i >> 6, cc = i & 63;
        WtL[cc][k] = (_Float16)W[i];   // W[k*64+cc]
    }
    const _Float16 we0h = (_Float16)We[c], we1h = (_Float16)We[64 + c];
    const h2vec we2f = {we0h, we1h};              // for single-edge tail
    const h2vec we02 = {we0h, we0h};              // splats for pair path
    const h2vec we12 = {we1h, we1h};
    const float becf = be[c];
    const h2vec bec2 = {(_Float16)becf, (_Float16)becf};
    const h2vec zero2 = {(_Float16)0.f, (_Float16)0.f};
    const h2vec one2 = {(_Float16)1.f, (_Float16)1.f};
    const float sj = g[c] * rsqrtf(rv[c] + BN_EPS);
    const float cj = (b[c] - rm[c]) * sj + bt[c];
    const unsigned short* hin_us = (const unsigned short*)hin;
    __syncthreads();

    const int n = blockIdx.x * 4 + w;
    const int rs = off[n], re = off[n + 1];
    const __half hc16 = hin[(size_t)n * 64 + c];  // hoisted center load
    float acc = 0.f;
    for (int base = rs; base < re; base += 64) {
        const int cnt = min(64, re - base);
        int2 rec = make_int2(0, 0);
        if (c < cnt) rec = edges[base + c];  // one coalesced wave-wide record load
        for (int j = 0; j < cnt; j += 16) {
            int hvr[16];
#pragma unroll
            for (int u = 0; u < 16; ++u) {
                int idx = j + u; if (idx > cnt - 1) idx = cnt - 1;  // clamp: dup loads hit L1
                int s = __builtin_amdgcn_readlane(rec.x, idx);
                hvr[u] = hin_us[(size_t)s * 64 + c];  // 16 gathers in flight (zext ushort)
            }
#pragma unroll
            for (int p = 0; p < 8; ++p) {
                const int e0 = j + 2 * p;
                if (e0 + 1 < cnt) {
                    int pk0 = __builtin_amdgcn_readlane(rec.y, e0);
                    int pk1 = __builtin_amdgcn_readlane(rec.y, e0 + 1);
                    int axp = (pk1 << 16) | (pk0 & 0xffff);              // scalar packs
                    int ayp = (pk1 & 0xffff0000) | ((unsigned)pk0 >> 16);
                    int h01 = (hvr[2 * p + 1] << 16) | hvr[2 * p];
                    h2vec q2 = __builtin_elementwise_fma(__builtin_bit_cast(h2vec, axp), we02, bec2);
                    q2 = __builtin_elementwise_fma(__builtin_bit_cast(h2vec, ayp), we12, q2);
                    h2vec m = __builtin_bit_cast(h2vec, h01) + q2;
                    m = __builtin_elementwise_max(m, zero2);
                    acc = __builtin_amdgcn_fdot2(m, one2, acc, false);
                } else if (e0 < cnt) {
                    int pk0 = __builtin_amdgcn_readlane(rec.y, e0);
                    float q = __builtin_amdgcn_fdot2(__builtin_bit_cast(h2vec, pk0), we2f, becf, false);
                    __half hh = __ushort_as_half((unsigned short)hvr[2 * p]);
                    acc += fmaxf(__half2float(hh) + q, 0.f);
                }
            }
        }
    }
    const float hc = __half2float(hc16);
    uL[w][c] = (_Float16)(hc + acc);
    // wave-private LDS reuse: lgkmcnt ordering suffices (validated round 2)
    float z = 0.f;
    const h4vec* u4p = (const h4vec*)uL[w];       // 128B-aligned row, broadcast reads
    const h4vec* wt4p = (const h4vec*)&WtL[c][0]; // c*136B, 8B-aligned
#pragma unroll
    for (int k4 = 0; k4 < 16; ++k4) {
        h4vec uu = u4p[k4];
        h4vec ww = wt4p[k4];
        h2vec ul = __builtin_shufflevector(uu, uu, 0, 1);
        h2vec uh = __builtin_shufflevector(uu, uu, 2, 3);
        h2vec wl = __builtin_shufflevector(ww, ww, 0, 1);
        h2vec wh = __builtin_shufflevector(ww, ww, 2, 3);
        z = __builtin_amdgcn_fdot2(ul, wl, z, false);
        z = __builtin_amdgcn_fdot2(uh, wh, z, false);
    }
    hout[(size_t)n * 64 + c] = __float2half(fmaxf(fmaf(z, sj, cj), 0.f) + hc);
}

// ---------------- Pool (mean+max per graph) + classifier ----------------
__global__ __launch_bounds__(256) void k_pool(
    const __half* __restrict__ h, const int* __restrict__ batch,
    const float* __restrict__ Wc1, const float* __restrict__ bc1,
    const float* __restrict__ Wc2, const float* __restrict__ bc2,
    float* __restrict__ out) {
    __shared__ float psum[4][64];
    __shared__ float pmax[4][64];
    __shared__ float pool[128];
    __shared__ float hid[64];
    const int t = threadIdx.x, w = t >> 6, c = t & 63;
    const int g = blockIdx.x;
    int lo = 0, hi = N_NODES;
    while (lo < hi) { int mid = (lo + hi) >> 1; if (batch[mid] < g) lo = mid + 1; else hi = mid; }
    int start = lo;
    hi = N_NODES;
    while (lo < hi) { int mid = (lo + hi) >> 1; if (batch[mid] < g + 1) lo = mid + 1; else hi = mid; }
    int end = lo;

    float s = 0.f, m = -3.4e38f;
    for (int i = start + w; i < end; i += 4) {
        float v = __half2float(h[(size_t)i * 64 + c]);
        s += v;
        m = fmaxf(m, v);
    }
    psum[w][c] = s;
    pmax[w][c] = m;
    __syncthreads();
    if (w == 0) {
        float ss = psum[0][c] + psum[1][c] + psum[2][c] + psum[3][c];
        float mm = fmaxf(fmaxf(pmax[0][c], pmax[1][c]), fmaxf(pmax[2][c], pmax[3][c]));
        int cnt = end - start;
        pool[c] = ss / fmaxf((float)cnt, 1.f);
        pool[64 + c] = (cnt > 0) ? mm : 0.f;
    }
    __syncthreads();
    if (t < 64) {
        float z = bc1[t];
#pragma unroll 8
        for (int k = 0; k < 128; ++k) z = fmaf(pool[k], Wc1[k * 64 + t], z);
        hid[t] = fmaxf(z, 0.f);
    }
    __syncthreads();
    if (t < N_CLS) {
        float z = bc2[t];
#pragma unroll
        for (int k = 0; k < 64; ++k) z = fmaf(hid[k], Wc2[k * N_CLS + t], z);
        out[g * N_CLS + t] = z;
    }
}

extern "C" void kernel_launch(void* const* d_in, const int* in_sizes, int n_in,
                              void* d_out, int out_size, void* d_ws, size_t ws_size,
                              hipStream_t stream) {
    const float* x     = (const float*)d_in[0];
    const int*   ei    = (const int*)d_in[1];
    const float* ea    = (const float*)d_in[2];
    const int*   batch = (const int*)d_in[3];
    const float* We1 = (const float*)d_in[4],  *be1 = (const float*)d_in[5];
    const float* We2 = (const float*)d_in[6],  *be2 = (const float*)d_in[7];
    const float* We3 = (const float*)d_in[8],  *be3 = (const float*)d_in[9];
    const float* W1 = (const float*)d_in[10], *b1 = (const float*)d_in[11];
    const float* g1 = (const float*)d_in[12], *bt1 = (const float*)d_in[13];
    const float* rm1 = (const float*)d_in[14], *rv1 = (const float*)d_in[15];
    const float* W2 = (const float*)d_in[16], *b2 = (const float*)d_in[17];
    const float* g2 = (const float*)d_in[18], *bt2 = (const float*)d_in[19];
    const float* rm2 = (const float*)d_in[20], *rv2 = (const float*)d_in[21];
    const float* W3 = (const float*)d_in[22], *b3 = (const float*)d_in[23];
    const float* g3 = (const float*)d_in[24], *bt3 = (const float*)d_in[25];
    const float* rm3 = (const float*)d_in[26], *rv3 = (const float*)d_in[27];
    const float* Wr = (const float*)d_in[28], *br = (const float*)d_in[29];
    const float* Wc1 = (const float*)d_in[30], *bc1 = (const float*)d_in[31];
    const float* Wc2 = (const float*)d_in[32], *bc2 = (const float*)d_in[33];

    int* off    = (int*)d_ws;                   // N+4
    int* gcount = off + (N_NODES + 4);          // 1024 (NB=1000, zero-padded)
    int* bbase  = gcount + 1024;                // 1024
    int2* edges = (int2*)(bbase + 1024);        // E * 8B packed records
    int2* stage = edges + E_EDGES;              // NB*BCAP * 8B fixed bucket regions
    __half* hA  = (__half*)(stage + (size_t)NB * BCAP);  // N*64 fp16
    __half* hB  = hA + (size_t)N_NODES * 64;    // N*64 fp16

    hipMemsetAsync(gcount, 0, 1024 * sizeof(int), stream);

    const int* src = ei;
    const int* dst = ei + E_EDGES;

    k_bin<<<E_EDGES / TILE, 256, 0, stream>>>(src, dst, (const float2*)ea, gcount, stage);
    k_bscan<<<1, 256, 0, stream>>>(gcount, bbase, off);
    k_final<<<NB, 256, 0, stream>>>(gcount, bbase, stage, off, edges);

    const int gine_blocks = N_NODES / 4;  // one node per wave, 4 waves/block
    k_gine12<<<gine_blocks, 256, 0, stream>>>(x, hA, off, edges,
                                              We1, be1, W1, b1, g1, bt1, rm1, rv1, Wr, br);
    k_gine64<<<gine_blocks, 256, 0, stream>>>(hA, hB, off, edges,
                                              We2, be2, W2, b2, g2, bt2, rm2, rv2);
    k_gine64<<<gine_blocks, 256, 0, stream>>>(hB, hA, off, edges,
                                              We3, be3, W3, b3, g3, bt3, rm3, rv3);
    k_pool<<<G_GRAPHS, 256, 0, stream>>>(hA, batch, Wc1, bc1, Wc2, bc2, (float*)d_out);
}